// Round 17
// baseline (114.246 us; speedup 1.0000x reference)
//
#include <hip/hip_runtime.h>
#include <math.h>

#define NB   2
#define NPTS 262144      // 64^3 points per batch

typedef __attribute__((ext_vector_type(8))) __bf16 bf16x8;
typedef __attribute__((ext_vector_type(4))) float  f32x4;

__device__ __forceinline__ float gelu_fast(float v) {
    float t  = v * v;
    float z2 = v * (-2.302208f + -0.1029432f * t);
    float e  = __builtin_amdgcn_exp2f(z2);
    return v * __builtin_amdgcn_rcpf(1.0f + e);
}

__device__ __forceinline__ unsigned short bf16_rn(float f) {
    unsigned u = __builtin_bit_cast(unsigned, f);
    u += 0x7fffu + ((u >> 16) & 1u);
    return (unsigned short)(u >> 16);
}

// ---------------------------------------------------------------------------
// Pass 1 (exact R15 champion body + counter reset): coalesced float4 a-loads;
// bf16-convert once in staging; packed u32 pairs to per-wave LDS + contiguous
// abf dwordx2 stores; fragments via one ds_read_b32 + unpack.
// ---------------------------------------------------------------------------
template<bool WRITE_ABF>
__global__ __launch_bounds__(256)
void pass1_kernel(const float* __restrict__ a, const float* __restrict__ x,
                  const float* __restrict__ mx, float* __restrict__ part,
                  unsigned* __restrict__ abf, unsigned* __restrict__ counter,
                  int NPB)
{
    __shared__ float4 xs[4][32];
    __shared__ float wsum[32 * 129];
    __shared__ __align__(16) unsigned atile[4][512];   // per-wave 32pt x 16 u32

    const int t = threadIdx.x, wave = t >> 6, lane = t & 63;
    const int l15 = lane & 15, l4 = lane >> 4;
    const int blk = blockIdx.x, b = blk / NPB, pb = blk % NPB;
    const int ppb = NPTS / NPB;
    const int chunks = ppb >> 5;
    const long base = (long)b * NPTS + (long)pb * ppb;

    if (blk == 0 && t == 0) counter[0] = 0;   // reset for reduceVmat (ordered by boundary)

    float m0[4], m1[4], m2[4];
    #pragma unroll
    for (int ct = 0; ct < 4; ++ct) {
        int g = l15 + 16 * ct;
        m0[ct] = mx[g*3]; m1[ct] = mx[g*3+1]; m2[ct] = mx[g*3+2];
    }

    f32x4 acc[2][8];
    #pragma unroll
    for (int rt = 0; rt < 2; ++rt)
        #pragma unroll
        for (int ct = 0; ct < 8; ++ct)
            acc[rt][ct] = f32x4{0.f, 0.f, 0.f, 0.f};

    for (int ci = wave; ci < chunks; ci += 4) {
        const long pc = base + ((long)ci << 5);

        // stage x (per-wave slot, same-wave use)
        if (lane < 32) {
            const float* xq = x + (pc + lane) * 3;
            xs[wave][lane] = make_float4(xq[0], xq[1], xq[2], 0.f);
        }

        // stage a: coalesced float4 load -> bf16 pack -> LDS + contiguous abf
        unsigned* aw = &atile[wave][0];
        #pragma unroll
        for (int q = 0; q < 4; ++q) {
            float4 v = *(const float4*)(a + pc * 32 + q * 256 + lane * 4);
            unsigned u0 = (unsigned)bf16_rn(v.x) | ((unsigned)bf16_rn(v.y) << 16);
            unsigned u1 = (unsigned)bf16_rn(v.z) | ((unsigned)bf16_rn(v.w) << 16);
            int idx = q * 128 + (lane >> 3) * 16 + (lane & 7) * 2;
            aw[idx]     = u0;
            aw[idx + 1] = u1;
            if (WRITE_ABF)
                *(uint2*)(abf + pc * 16 + idx) = make_uint2(u0, u1);
        }

        // fragments: one ds_read_b32 + unpack (no cvt)
        bf16x8 afr[2];
        #pragma unroll
        for (int j = 0; j < 8; ++j) {
            unsigned u = aw[(l4*8 + j) * 16 + l15];
            afr[0][j] = __builtin_bit_cast(__bf16, (unsigned short)(u & 0xffffu));
            afr[1][j] = __builtin_bit_cast(__bf16, (unsigned short)(u >> 16));
        }

        float4 xp[8];
        #pragma unroll
        for (int j = 0; j < 8; ++j) xp[j] = xs[wave][l4*8 + j];

        #pragma unroll
        for (int ct = 0; ct < 4; ++ct) {
            bf16x8 bc, bs;
            #pragma unroll
            for (int j = 0; j < 8; ++j) {
                float d = xp[j].x*m0[ct] + xp[j].y*m1[ct] + xp[j].z*m2[ct];
                bc[j] = (__bf16)__builtin_amdgcn_cosf(d);   // cos(2*pi*d)
                bs[j] = (__bf16)__builtin_amdgcn_sinf(d);
            }
            #pragma unroll
            for (int rt = 0; rt < 2; ++rt) {
                acc[rt][ct]   = __builtin_amdgcn_mfma_f32_16x16x32_bf16(afr[rt], bc, acc[rt][ct],   0, 0, 0);
                acc[rt][ct+4] = __builtin_amdgcn_mfma_f32_16x16x32_bf16(afr[rt], bs, acc[rt][ct+4], 0, 0, 0);
            }
        }
    }

    // cross-wave reduction in LDS; D row m' = l4*4+r -> true channel 2*m'+rt
    for (int w = 0; w < 4; ++w) {
        if (wave == w) {
            #pragma unroll
            for (int rt = 0; rt < 2; ++rt)
                #pragma unroll
                for (int ct = 0; ct < 8; ++ct)
                    #pragma unroll
                    for (int r = 0; r < 4; ++r) {
                        int i = 2 * (l4*4 + r) + rt;
                        int c = ((ct & 3) * 16) + l15 + ((ct & 4) ? 64 : 0);
                        int id = i * 129 + c;
                        float v = acc[rt][ct][r];
                        if (w == 0) wsum[id] = v; else wsum[id] += v;
                    }
        }
        __syncthreads();
    }
    for (int idx = t; idx < 4096; idx += 256) {
        int i = idx >> 7, c = idx & 127;
        part[(long)blk * 4096 + idx] = wsum[i * 129 + c];
    }
}

// ---------------------------------------------------------------------------
// Merged reduce + vmat: grid NB*128. Each block reduces 32 W-entries (R15
// reduceW body). Last finished block (device-scope counter) computes vmat
// for both batches -- deterministic: single block, fully-reduced Wf.
// ---------------------------------------------------------------------------
__global__ __launch_bounds__(256)
void reduceVmat_kernel(const float* __restrict__ part, float* __restrict__ Wf,
                       const float* __restrict__ ma, const float* __restrict__ mu,
                       const float* __restrict__ fcw, unsigned short* __restrict__ Vb,
                       unsigned* __restrict__ counter, int NPB)
{
    __shared__ float red[8][33];
    __shared__ float Ws[4096];
    __shared__ float Qs[1024];
    __shared__ unsigned lastFlag;

    const int t = threadIdx.x;
    const int b = blockIdx.x >> 7;
    const int jb = (blockIdx.x & 127) * 32;
    const int jj = jb + (t & 31), seg = t >> 5;
    const float* p = part + (long)b * NPB * 4096 + jj;
    float s = 0.f;
    for (int pb = seg; pb < NPB; pb += 8) s += p[(long)pb * 4096];
    red[seg][t & 31] = s;
    __syncthreads();
    if (t < 32) {
        float r = 0.f;
        #pragma unroll
        for (int q = 0; q < 8; ++q) r += red[q][t];
        Wf[b * 4096 + jb + t] = r;
    }

    // last-block-done handoff (release: fence before atomic)
    __threadfence();
    if (t == 0) {
        unsigned old = atomicAdd(counter, 1u);
        lastFlag = (old == gridDim.x - 1) ? 1u : 0u;
    }
    __syncthreads();
    if (!lastFlag) return;
    __threadfence();   // acquire: all Wf writes visible

    for (int bb = 0; bb < NB; ++bb) {
        for (int i = t; i < 4096; i += 256) Ws[i] = Wf[bb * 4096 + i];
        __syncthreads();
        for (int i = t; i < 1024; i += 256) {
            int o = i >> 5, ii = i & 31;
            float s2 = 0.f;
            for (int f = 0; f < 64; ++f) s2 += mu[f*32 + o] * ma[f*32 + ii];
            Qs[i] = s2;
        }
        __syncthreads();
        const float invN = 1.f / 262144.f;
        for (int i = t; i < 5120; i += 256) {
            int k = i >> 5, o = i & 31;
            float v;
            if (k < 128) {
                int g = k & 63, off = (k >= 64) ? 64 : 0;
                float s2 = 0.f;
                for (int q = 0; q < 32; ++q) s2 += Qs[o*32 + q] * Ws[q*128 + off + g];
                v = s2 * invN;
            } else {
                v = fcw[(k - 128) * 32 + o];
            }
            Vb[bb * 5120 + i] = bf16_rn(v);
        }
        __syncthreads();
    }
}

// ---------------------------------------------------------------------------
// Pass 2 (R15, unchanged)
// ---------------------------------------------------------------------------
template<bool READ_ABF>
__global__ __launch_bounds__(256)
void pass2_kernel(const float* __restrict__ a, const unsigned* __restrict__ abf,
                  const float* __restrict__ x, const unsigned short* __restrict__ Vb,
                  const float* __restrict__ fcb, const float* __restrict__ my,
                  float* __restrict__ out)
{
    __shared__ float4 xs[4][32];
    __shared__ float4 mys[64];
    __shared__ __align__(16) float st[4][16][32];
    const int t = threadIdx.x, wave = t >> 6, lane = t & 63;
    const int l15 = lane & 15, l4 = lane >> 4;
    const int blk = blockIdx.x, b = blk >> 9, lb = blk & 511;
    const long base = (long)b * NPTS + (long)lb * 512;

    if (t < 64) { const float* mq = my + t*3; mys[t] = make_float4(mq[0], mq[1], mq[2], 0.f); }

    bf16x8 bfr[5][2];
    {
        const unsigned short* vb = Vb + b * 5120;
        #pragma unroll
        for (int c = 0; c < 5; ++c)
            #pragma unroll
            for (int ct = 0; ct < 2; ++ct) {
                bf16x8 tmp;
                #pragma unroll
                for (int j = 0; j < 8; ++j) {
                    unsigned short uv = vb[(32*c + l4*8 + j) * 32 + l15 + 16*ct];
                    tmp[j] = __builtin_bit_cast(__bf16, uv);
                }
                bfr[c][ct] = tmp;
            }
    }
    const float bias0 = fcb[l15], bias1 = fcb[l15 + 16];
    __syncthreads();

    for (int ci = wave; ci < 16; ci += 4) {
        const long pc = base + ((long)ci << 5);

        if (lane < 32) {
            const float* xq = x + (pc + lane) * 3;
            xs[wave][lane] = make_float4(xq[0], xq[1], xq[2], 0.f);
        }
        bf16x8 afr[2];
        #pragma unroll
        for (int rt = 0; rt < 2; ++rt) {
            if (READ_ABF) {
                afr[rt] = __builtin_bit_cast(bf16x8,
                    *(const uint4*)(abf + (pc + l15 + 16*rt) * 16 + l4*4));
            } else {
                const float* ap = a + (pc + l15 + 16*rt) * 32 + l4*8;
                float4 a0 = *(const float4*)ap;
                float4 a1 = *(const float4*)(ap + 4);
                afr[rt][0] = (__bf16)a0.x; afr[rt][1] = (__bf16)a0.y;
                afr[rt][2] = (__bf16)a0.z; afr[rt][3] = (__bf16)a0.w;
                afr[rt][4] = (__bf16)a1.x; afr[rt][5] = (__bf16)a1.y;
                afr[rt][6] = (__bf16)a1.z; afr[rt][7] = (__bf16)a1.w;
            }
        }

        float4 xp0 = xs[wave][l15];
        float4 xp1 = xs[wave][l15 + 16];

        f32x4 acc[2][2];
        #pragma unroll
        for (int rt = 0; rt < 2; ++rt)
            #pragma unroll
            for (int ct = 0; ct < 2; ++ct) acc[rt][ct] = f32x4{0.f,0.f,0.f,0.f};

        #pragma unroll
        for (int gt = 0; gt < 2; ++gt) {
            bf16x8 ac[2], as2[2];
            #pragma unroll
            for (int j = 0; j < 8; ++j) {
                float4 m = mys[gt*32 + l4*8 + j];
                float d0 = xp0.x*m.x + xp0.y*m.y + xp0.z*m.z;
                float d1 = xp1.x*m.x + xp1.y*m.y + xp1.z*m.z;
                ac[0][j]  = (__bf16)__builtin_amdgcn_cosf(d0);
                as2[0][j] = (__bf16)__builtin_amdgcn_sinf(d0);
                ac[1][j]  = (__bf16)__builtin_amdgcn_cosf(d1);
                as2[1][j] = (__bf16)__builtin_amdgcn_sinf(d1);
            }
            #pragma unroll
            for (int rt = 0; rt < 2; ++rt)
                #pragma unroll
                for (int ct = 0; ct < 2; ++ct) {
                    acc[rt][ct] = __builtin_amdgcn_mfma_f32_16x16x32_bf16(ac[rt],  bfr[gt][ct],   acc[rt][ct], 0, 0, 0);
                    acc[rt][ct] = __builtin_amdgcn_mfma_f32_16x16x32_bf16(as2[rt], bfr[2+gt][ct], acc[rt][ct], 0, 0, 0);
                }
        }
        #pragma unroll
        for (int rt = 0; rt < 2; ++rt) {
            #pragma unroll
            for (int ct = 0; ct < 2; ++ct) {
                acc[rt][ct] = __builtin_amdgcn_mfma_f32_16x16x32_bf16(afr[rt], bfr[4][ct], acc[rt][ct], 0, 0, 0);
                float bias = ct ? bias1 : bias0;
                #pragma unroll
                for (int r = 0; r < 4; ++r)
                    st[wave][l4*4 + r][l15 + 16*ct] = gelu_fast(acc[rt][ct][r] + bias);
            }
            {
                int row = lane >> 3;
                int c4  = (lane & 7) * 4;
                float4 v0 = *(const float4*)&st[wave][row][c4];
                float4 v1 = *(const float4*)&st[wave][row + 8][c4];
                *(float4*)&out[(pc + 16*rt + row) * 32 + c4]     = v0;
                *(float4*)&out[(pc + 16*rt + row + 8) * 32 + c4] = v1;
            }
        }
    }
}

// ---------------------------------------------------------------------------
extern "C" void kernel_launch(void* const* d_in, const int* in_sizes, int n_in,
                              void* d_out, int out_size, void* d_ws, size_t ws_size,
                              hipStream_t stream)
{
    const float* a   = (const float*)d_in[0];
    const float* x   = (const float*)d_in[1];
    const float* ma  = (const float*)d_in[3];
    const float* mx  = (const float*)d_in[4];
    const float* my  = (const float*)d_in[5];
    const float* mu  = (const float*)d_in[6];
    const float* fcw = (const float*)d_in[7];
    const float* fcb = (const float*)d_in[8];
    float* out = (float*)d_out;

    const size_t WfB  = (size_t)NB * 4096 * 4;
    const size_t VbB  = (size_t)NB * 5120 * 2;
    const size_t abfB = (size_t)NB * NPTS * 16 * 4;   // 33.5 MB u32 relay

    int NPB = 256;
    bool use_abf = ws_size >= (size_t)NB * NPB * 4096 * 4 + WfB + VbB + abfB + 256;
    if (!use_abf) {
        while (NPB > 32 &&
               ws_size < (size_t)NB * NPB * 4096 * 4 + WfB + VbB + 256)
            NPB >>= 1;
    }

    float* part = (float*)d_ws;
    float* Wf = part + (size_t)NB * NPB * 4096;
    unsigned short* Vb = (unsigned short*)(Wf + NB * 4096);
    unsigned* abf = (unsigned*)(Vb + NB * 5120);
    unsigned* counter = use_abf ? (abf + (size_t)NB * NPTS * 16)
                                : (unsigned*)(Vb + NB * 5120);

    if (use_abf)
        pass1_kernel<true><<<NB * NPB, 256, 0, stream>>>(a, x, mx, part, abf, counter, NPB);
    else
        pass1_kernel<false><<<NB * NPB, 256, 0, stream>>>(a, x, mx, part, abf, counter, NPB);

    reduceVmat_kernel<<<NB * 128, 256, 0, stream>>>(part, Wf, ma, mu, fcw, Vb, counter, NPB);

    if (use_abf)
        pass2_kernel<true><<<NB * 512, 256, 0, stream>>>(a, abf, x, Vb, fcb, my, out);
    else
        pass2_kernel<false><<<NB * 512, 256, 0, stream>>>(a, abf, x, Vb, fcb, my, out);
}

// Round 18
// 79.702 us; speedup vs baseline: 1.4334x; 1.4334x over previous
//
#include <hip/hip_runtime.h>
#include <math.h>

#define NB   2
#define NPTS 262144      // 64^3 points per batch

typedef __attribute__((ext_vector_type(8))) __bf16 bf16x8;
typedef __attribute__((ext_vector_type(4))) float  f32x4;

__device__ __forceinline__ float gelu_fast(float v) {
    float t  = v * v;
    float z2 = v * (-2.302208f + -0.1029432f * t);
    float e  = __builtin_amdgcn_exp2f(z2);
    return v * __builtin_amdgcn_rcpf(1.0f + e);
}

__device__ __forceinline__ unsigned short bf16_rn(float f) {
    unsigned u = __builtin_bit_cast(unsigned, f);
    u += 0x7fffu + ((u >> 16) & 1u);
    return (unsigned short)(u >> 16);
}

// ---------------------------------------------------------------------------
// Pass 1 (R15 champion): coalesced float4 a-loads; bf16-convert ONCE in the
// staging loop; packed u32 pairs go to per-wave LDS (fragment redistribution)
// and to abf via fully-contiguous dwordx2 stores. Fragments from one
// ds_read_b32 + bit-unpack. No cross-wave sync in the main loop.
// ---------------------------------------------------------------------------
template<bool WRITE_ABF>
__global__ __launch_bounds__(256)
void pass1_kernel(const float* __restrict__ a, const float* __restrict__ x,
                  const float* __restrict__ mx, float* __restrict__ part,
                  unsigned* __restrict__ abf, int NPB)
{
    __shared__ float4 xs[4][32];
    __shared__ float wsum[32 * 129];
    __shared__ __align__(16) unsigned atile[4][512];   // per-wave 32pt x 16 u32

    const int t = threadIdx.x, wave = t >> 6, lane = t & 63;
    const int l15 = lane & 15, l4 = lane >> 4;
    const int blk = blockIdx.x, b = blk / NPB, pb = blk % NPB;
    const int ppb = NPTS / NPB;
    const int chunks = ppb >> 5;
    const long base = (long)b * NPTS + (long)pb * ppb;

    float m0[4], m1[4], m2[4];
    #pragma unroll
    for (int ct = 0; ct < 4; ++ct) {
        int g = l15 + 16 * ct;
        m0[ct] = mx[g*3]; m1[ct] = mx[g*3+1]; m2[ct] = mx[g*3+2];
    }

    f32x4 acc[2][8];
    #pragma unroll
    for (int rt = 0; rt < 2; ++rt)
        #pragma unroll
        for (int ct = 0; ct < 8; ++ct)
            acc[rt][ct] = f32x4{0.f, 0.f, 0.f, 0.f};

    for (int ci = wave; ci < chunks; ci += 4) {
        const long pc = base + ((long)ci << 5);

        // stage x (per-wave slot, same-wave use)
        if (lane < 32) {
            const float* xq = x + (pc + lane) * 3;
            xs[wave][lane] = make_float4(xq[0], xq[1], xq[2], 0.f);
        }

        // stage a: coalesced float4 load -> bf16 pack -> LDS + contiguous abf
        unsigned* aw = &atile[wave][0];
        #pragma unroll
        for (int q = 0; q < 4; ++q) {
            float4 v = *(const float4*)(a + pc * 32 + q * 256 + lane * 4);
            unsigned u0 = (unsigned)bf16_rn(v.x) | ((unsigned)bf16_rn(v.y) << 16);
            unsigned u1 = (unsigned)bf16_rn(v.z) | ((unsigned)bf16_rn(v.w) << 16);
            int idx = q * 128 + (lane >> 3) * 16 + (lane & 7) * 2;
            aw[idx]     = u0;
            aw[idx + 1] = u1;
            if (WRITE_ABF)
                *(uint2*)(abf + pc * 16 + idx) = make_uint2(u0, u1);
        }

        // fragments: one ds_read_b32 + unpack (no cvt)
        bf16x8 afr[2];
        #pragma unroll
        for (int j = 0; j < 8; ++j) {
            unsigned u = aw[(l4*8 + j) * 16 + l15];
            afr[0][j] = __builtin_bit_cast(__bf16, (unsigned short)(u & 0xffffu));
            afr[1][j] = __builtin_bit_cast(__bf16, (unsigned short)(u >> 16));
        }

        float4 xp[8];
        #pragma unroll
        for (int j = 0; j < 8; ++j) xp[j] = xs[wave][l4*8 + j];

        #pragma unroll
        for (int ct = 0; ct < 4; ++ct) {
            bf16x8 bc, bs;
            #pragma unroll
            for (int j = 0; j < 8; ++j) {
                float d = xp[j].x*m0[ct] + xp[j].y*m1[ct] + xp[j].z*m2[ct];
                bc[j] = (__bf16)__builtin_amdgcn_cosf(d);   // cos(2*pi*d)
                bs[j] = (__bf16)__builtin_amdgcn_sinf(d);
            }
            #pragma unroll
            for (int rt = 0; rt < 2; ++rt) {
                acc[rt][ct]   = __builtin_amdgcn_mfma_f32_16x16x32_bf16(afr[rt], bc, acc[rt][ct],   0, 0, 0);
                acc[rt][ct+4] = __builtin_amdgcn_mfma_f32_16x16x32_bf16(afr[rt], bs, acc[rt][ct+4], 0, 0, 0);
            }
        }
    }

    // cross-wave reduction in LDS; D row m' = l4*4+r -> true channel 2*m'+rt
    for (int w = 0; w < 4; ++w) {
        if (wave == w) {
            #pragma unroll
            for (int rt = 0; rt < 2; ++rt)
                #pragma unroll
                for (int ct = 0; ct < 8; ++ct)
                    #pragma unroll
                    for (int r = 0; r < 4; ++r) {
                        int i = 2 * (l4*4 + r) + rt;
                        int c = ((ct & 3) * 16) + l15 + ((ct & 4) ? 64 : 0);
                        int id = i * 129 + c;
                        float v = acc[rt][ct][r];
                        if (w == 0) wsum[id] = v; else wsum[id] += v;
                    }
        }
        __syncthreads();
    }
    for (int idx = t; idx < 4096; idx += 256) {
        int i = idx >> 7, c = idx & 127;
        part[(long)blk * 4096 + idx] = wsum[i * 129 + c];
    }
}

// ---------------------------------------------------------------------------
// Reduce partials -> Wf[b][4096].  (R15, unchanged)
// ---------------------------------------------------------------------------
__global__ __launch_bounds__(256)
void reduceW_kernel(const float* __restrict__ part, float* __restrict__ Wf, int NPB)
{
    __shared__ float red[8][33];
    const int t = threadIdx.x;
    const int b = blockIdx.x >> 7;
    const int jb = (blockIdx.x & 127) * 32;
    const int jj = jb + (t & 31), seg = t >> 5;
    const float* p = part + (long)b * NPB * 4096 + jj;
    float s = 0.f;
    for (int pb = seg; pb < NPB; pb += 8) s += p[(long)pb * 4096];
    red[seg][t & 31] = s;
    __syncthreads();
    if (t < 32) {
        float r = 0.f;
        #pragma unroll
        for (int q = 0; q < 8; ++q) r += red[q][t];
        Wf[b * 4096 + jb + t] = r;
    }
}

// ---------------------------------------------------------------------------
// vmat (R15, unchanged)
// ---------------------------------------------------------------------------
__global__ __launch_bounds__(256)
void vmat_kernel(const float* __restrict__ Wf, const float* __restrict__ ma,
                 const float* __restrict__ mu, const float* __restrict__ fcw,
                 unsigned short* __restrict__ Vb)
{
    __shared__ float Ws[4096];
    __shared__ float Qs[32][32];
    const int t = threadIdx.x, b = blockIdx.x;
    for (int i = t; i < 4096; i += 256) Ws[i] = Wf[b * 4096 + i];
    __syncthreads();
    for (int i = t; i < 1024; i += 256) {
        int o = i >> 5, ii = i & 31;
        float s = 0.f;
        for (int f = 0; f < 64; ++f) s += mu[f*32 + o] * ma[f*32 + ii];
        Qs[o][ii] = s;
    }
    __syncthreads();
    const float invN = 1.f / 262144.f;
    for (int i = t; i < 5120; i += 256) {
        int k = i >> 5, o = i & 31;
        float v;
        if (k < 128) {
            int g = k & 63, off = (k >= 64) ? 64 : 0;
            float s = 0.f;
            for (int q = 0; q < 32; ++q) s += Qs[o][q] * Ws[q*128 + off + g];
            v = s * invN;
        } else {
            v = fcw[(k - 128) * 32 + o];
        }
        Vb[b * 5120 + i] = bf16_rn(v);
    }
}

// ---------------------------------------------------------------------------
// Pass 2 (R15, unchanged: prefetchless chunk loop with per-wave LDS-staged
// coalesced output stores; a from bf16 relay)
// ---------------------------------------------------------------------------
template<bool READ_ABF>
__global__ __launch_bounds__(256)
void pass2_kernel(const float* __restrict__ a, const unsigned* __restrict__ abf,
                  const float* __restrict__ x, const unsigned short* __restrict__ Vb,
                  const float* __restrict__ fcb, const float* __restrict__ my,
                  float* __restrict__ out)
{
    __shared__ float4 xs[4][32];
    __shared__ float4 mys[64];
    __shared__ __align__(16) float st[4][16][32];
    const int t = threadIdx.x, wave = t >> 6, lane = t & 63;
    const int l15 = lane & 15, l4 = lane >> 4;
    const int blk = blockIdx.x, b = blk >> 9, lb = blk & 511;
    const long base = (long)b * NPTS + (long)lb * 512;

    if (t < 64) { const float* mq = my + t*3; mys[t] = make_float4(mq[0], mq[1], mq[2], 0.f); }

    bf16x8 bfr[5][2];
    {
        const unsigned short* vb = Vb + b * 5120;
        #pragma unroll
        for (int c = 0; c < 5; ++c)
            #pragma unroll
            for (int ct = 0; ct < 2; ++ct) {
                bf16x8 tmp;
                #pragma unroll
                for (int j = 0; j < 8; ++j) {
                    unsigned short uv = vb[(32*c + l4*8 + j) * 32 + l15 + 16*ct];
                    tmp[j] = __builtin_bit_cast(__bf16, uv);
                }
                bfr[c][ct] = tmp;
            }
    }
    const float bias0 = fcb[l15], bias1 = fcb[l15 + 16];
    __syncthreads();

    for (int ci = wave; ci < 16; ci += 4) {
        const long pc = base + ((long)ci << 5);

        if (lane < 32) {
            const float* xq = x + (pc + lane) * 3;
            xs[wave][lane] = make_float4(xq[0], xq[1], xq[2], 0.f);
        }
        bf16x8 afr[2];
        #pragma unroll
        for (int rt = 0; rt < 2; ++rt) {
            if (READ_ABF) {
                afr[rt] = __builtin_bit_cast(bf16x8,
                    *(const uint4*)(abf + (pc + l15 + 16*rt) * 16 + l4*4));
            } else {
                const float* ap = a + (pc + l15 + 16*rt) * 32 + l4*8;
                float4 a0 = *(const float4*)ap;
                float4 a1 = *(const float4*)(ap + 4);
                afr[rt][0] = (__bf16)a0.x; afr[rt][1] = (__bf16)a0.y;
                afr[rt][2] = (__bf16)a0.z; afr[rt][3] = (__bf16)a0.w;
                afr[rt][4] = (__bf16)a1.x; afr[rt][5] = (__bf16)a1.y;
                afr[rt][6] = (__bf16)a1.z; afr[rt][7] = (__bf16)a1.w;
            }
        }

        float4 xp0 = xs[wave][l15];
        float4 xp1 = xs[wave][l15 + 16];

        f32x4 acc[2][2];
        #pragma unroll
        for (int rt = 0; rt < 2; ++rt)
            #pragma unroll
            for (int ct = 0; ct < 2; ++ct) acc[rt][ct] = f32x4{0.f,0.f,0.f,0.f};

        #pragma unroll
        for (int gt = 0; gt < 2; ++gt) {
            bf16x8 ac[2], as2[2];
            #pragma unroll
            for (int j = 0; j < 8; ++j) {
                float4 m = mys[gt*32 + l4*8 + j];
                float d0 = xp0.x*m.x + xp0.y*m.y + xp0.z*m.z;
                float d1 = xp1.x*m.x + xp1.y*m.y + xp1.z*m.z;
                ac[0][j]  = (__bf16)__builtin_amdgcn_cosf(d0);
                as2[0][j] = (__bf16)__builtin_amdgcn_sinf(d0);
                ac[1][j]  = (__bf16)__builtin_amdgcn_cosf(d1);
                as2[1][j] = (__bf16)__builtin_amdgcn_sinf(d1);
            }
            #pragma unroll
            for (int rt = 0; rt < 2; ++rt)
                #pragma unroll
                for (int ct = 0; ct < 2; ++ct) {
                    acc[rt][ct] = __builtin_amdgcn_mfma_f32_16x16x32_bf16(ac[rt],  bfr[gt][ct],   acc[rt][ct], 0, 0, 0);
                    acc[rt][ct] = __builtin_amdgcn_mfma_f32_16x16x32_bf16(as2[rt], bfr[2+gt][ct], acc[rt][ct], 0, 0, 0);
                }
        }
        #pragma unroll
        for (int rt = 0; rt < 2; ++rt) {
            #pragma unroll
            for (int ct = 0; ct < 2; ++ct) {
                acc[rt][ct] = __builtin_amdgcn_mfma_f32_16x16x32_bf16(afr[rt], bfr[4][ct], acc[rt][ct], 0, 0, 0);
                float bias = ct ? bias1 : bias0;
                #pragma unroll
                for (int r = 0; r < 4; ++r)
                    st[wave][l4*4 + r][l15 + 16*ct] = gelu_fast(acc[rt][ct][r] + bias);
            }
            {
                int row = lane >> 3;
                int c4  = (lane & 7) * 4;
                float4 v0 = *(const float4*)&st[wave][row][c4];
                float4 v1 = *(const float4*)&st[wave][row + 8][c4];
                *(float4*)&out[(pc + 16*rt + row) * 32 + c4]     = v0;
                *(float4*)&out[(pc + 16*rt + row + 8) * 32 + c4] = v1;
            }
        }
    }
}

// ---------------------------------------------------------------------------
extern "C" void kernel_launch(void* const* d_in, const int* in_sizes, int n_in,
                              void* d_out, int out_size, void* d_ws, size_t ws_size,
                              hipStream_t stream)
{
    const float* a   = (const float*)d_in[0];
    const float* x   = (const float*)d_in[1];
    const float* ma  = (const float*)d_in[3];
    const float* mx  = (const float*)d_in[4];
    const float* my  = (const float*)d_in[5];
    const float* mu  = (const float*)d_in[6];
    const float* fcw = (const float*)d_in[7];
    const float* fcb = (const float*)d_in[8];
    float* out = (float*)d_out;

    const size_t WfB  = (size_t)NB * 4096 * 4;
    const size_t VbB  = (size_t)NB * 5120 * 2;
    const size_t abfB = (size_t)NB * NPTS * 16 * 4;   // 33.5 MB u32 relay

    int NPB = 256;
    bool use_abf = ws_size >= (size_t)NB * NPB * 4096 * 4 + WfB + VbB + abfB + 256;
    if (!use_abf) {
        while (NPB > 32 &&
               ws_size < (size_t)NB * NPB * 4096 * 4 + WfB + VbB + 256)
            NPB >>= 1;
    }

    float* part = (float*)d_ws;
    float* Wf = part + (size_t)NB * NPB * 4096;
    unsigned short* Vb = (unsigned short*)(Wf + NB * 4096);
    unsigned* abf = (unsigned*)(Vb + NB * 5120);

    if (use_abf)
        pass1_kernel<true><<<NB * NPB, 256, 0, stream>>>(a, x, mx, part, abf, NPB);
    else
        pass1_kernel<false><<<NB * NPB, 256, 0, stream>>>(a, x, mx, part, abf, NPB);

    reduceW_kernel<<<NB * 128, 256, 0, stream>>>(part, Wf, NPB);
    vmat_kernel<<<NB, 256, 0, stream>>>(Wf, ma, mu, fcw, Vb);

    if (use_abf)
        pass2_kernel<true><<<NB * 512, 256, 0, stream>>>(a, abf, x, Vb, fcb, my, out);
    else
        pass2_kernel<false><<<NB * 512, 256, 0, stream>>>(a, abf, x, Vb, fcb, my, out);
}

// Round 19
// 78.541 us; speedup vs baseline: 1.4546x; 1.0148x over previous
//
#include <hip/hip_runtime.h>
#include <math.h>

#define NB   2
#define NPTS 262144      // 64^3 points per batch

typedef __attribute__((ext_vector_type(8))) __bf16 bf16x8;
typedef __attribute__((ext_vector_type(4))) float  f32x4;

__device__ __forceinline__ float gelu_fast(float v) {
    float t  = v * v;
    float z2 = v * (-2.302208f + -0.1029432f * t);
    float e  = __builtin_amdgcn_exp2f(z2);
    return v * __builtin_amdgcn_rcpf(1.0f + e);
}

__device__ __forceinline__ unsigned short bf16_rn(float f) {
    unsigned u = __builtin_bit_cast(unsigned, f);
    u += 0x7fffu + ((u >> 16) & 1u);
    return (unsigned short)(u >> 16);
}

// ---------------------------------------------------------------------------
// Pass 1 (R15 champion minus the x LDS round-trip): x comes in as 6 float4
// broadcast global loads per chunk (same addr across each 16-lane group);
// a staged via coalesced float4 -> bf16 pack -> LDS + contiguous abf;
// fragments via one ds_read_b32 + unpack.
// ---------------------------------------------------------------------------
template<bool WRITE_ABF>
__global__ __launch_bounds__(256)
void pass1_kernel(const float* __restrict__ a, const float* __restrict__ x,
                  const float* __restrict__ mx, float* __restrict__ part,
                  unsigned* __restrict__ abf, int NPB)
{
    __shared__ float wsum[32 * 129];
    __shared__ __align__(16) unsigned atile[4][512];   // per-wave 32pt x 16 u32

    const int t = threadIdx.x, wave = t >> 6, lane = t & 63;
    const int l15 = lane & 15, l4 = lane >> 4;
    const int blk = blockIdx.x, b = blk / NPB, pb = blk % NPB;
    const int ppb = NPTS / NPB;
    const int chunks = ppb >> 5;
    const long base = (long)b * NPTS + (long)pb * ppb;

    float m0[4], m1[4], m2[4];
    #pragma unroll
    for (int ct = 0; ct < 4; ++ct) {
        int g = l15 + 16 * ct;
        m0[ct] = mx[g*3]; m1[ct] = mx[g*3+1]; m2[ct] = mx[g*3+2];
    }

    f32x4 acc[2][8];
    #pragma unroll
    for (int rt = 0; rt < 2; ++rt)
        #pragma unroll
        for (int ct = 0; ct < 8; ++ct)
            acc[rt][ct] = f32x4{0.f, 0.f, 0.f, 0.f};

    for (int ci = wave; ci < chunks; ci += 4) {
        const long pc = base + ((long)ci << 5);

        // x for this lane's 16-lane group: 24 contiguous floats, 16B-aligned
        // ((pc + l4*8) % 8 == 0 -> byte offset % 96 == 0). Broadcast loads.
        float xf[24];
        {
            const float* xq = x + (pc + l4*8) * 3;
            float4* xfv = (float4*)xf;
            #pragma unroll
            for (int q = 0; q < 6; ++q)
                xfv[q] = *(const float4*)(xq + q*4);
        }

        // stage a: coalesced float4 load -> bf16 pack -> LDS + contiguous abf
        unsigned* aw = &atile[wave][0];
        #pragma unroll
        for (int q = 0; q < 4; ++q) {
            float4 v = *(const float4*)(a + pc * 32 + q * 256 + lane * 4);
            unsigned u0 = (unsigned)bf16_rn(v.x) | ((unsigned)bf16_rn(v.y) << 16);
            unsigned u1 = (unsigned)bf16_rn(v.z) | ((unsigned)bf16_rn(v.w) << 16);
            int idx = q * 128 + (lane >> 3) * 16 + (lane & 7) * 2;
            aw[idx]     = u0;
            aw[idx + 1] = u1;
            if (WRITE_ABF)
                *(uint2*)(abf + pc * 16 + idx) = make_uint2(u0, u1);
        }

        // fragments: one ds_read_b32 + unpack (no cvt)
        bf16x8 afr[2];
        #pragma unroll
        for (int j = 0; j < 8; ++j) {
            unsigned u = aw[(l4*8 + j) * 16 + l15];
            afr[0][j] = __builtin_bit_cast(__bf16, (unsigned short)(u & 0xffffu));
            afr[1][j] = __builtin_bit_cast(__bf16, (unsigned short)(u >> 16));
        }

        #pragma unroll
        for (int ct = 0; ct < 4; ++ct) {
            bf16x8 bc, bs;
            #pragma unroll
            for (int j = 0; j < 8; ++j) {
                float d = xf[3*j]*m0[ct] + xf[3*j+1]*m1[ct] + xf[3*j+2]*m2[ct];
                bc[j] = (__bf16)__builtin_amdgcn_cosf(d);   // cos(2*pi*d)
                bs[j] = (__bf16)__builtin_amdgcn_sinf(d);
            }
            #pragma unroll
            for (int rt = 0; rt < 2; ++rt) {
                acc[rt][ct]   = __builtin_amdgcn_mfma_f32_16x16x32_bf16(afr[rt], bc, acc[rt][ct],   0, 0, 0);
                acc[rt][ct+4] = __builtin_amdgcn_mfma_f32_16x16x32_bf16(afr[rt], bs, acc[rt][ct+4], 0, 0, 0);
            }
        }
    }

    // cross-wave reduction in LDS; D row m' = l4*4+r -> true channel 2*m'+rt
    for (int w = 0; w < 4; ++w) {
        if (wave == w) {
            #pragma unroll
            for (int rt = 0; rt < 2; ++rt)
                #pragma unroll
                for (int ct = 0; ct < 8; ++ct)
                    #pragma unroll
                    for (int r = 0; r < 4; ++r) {
                        int i = 2 * (l4*4 + r) + rt;
                        int c = ((ct & 3) * 16) + l15 + ((ct & 4) ? 64 : 0);
                        int id = i * 129 + c;
                        float v = acc[rt][ct][r];
                        if (w == 0) wsum[id] = v; else wsum[id] += v;
                    }
        }
        __syncthreads();
    }
    for (int idx = t; idx < 4096; idx += 256) {
        int i = idx >> 7, c = idx & 127;
        part[(long)blk * 4096 + idx] = wsum[i * 129 + c];
    }
}

// ---------------------------------------------------------------------------
// Reduce partials -> Wf[b][4096].  (R15, unchanged)
// ---------------------------------------------------------------------------
__global__ __launch_bounds__(256)
void reduceW_kernel(const float* __restrict__ part, float* __restrict__ Wf, int NPB)
{
    __shared__ float red[8][33];
    const int t = threadIdx.x;
    const int b = blockIdx.x >> 7;
    const int jb = (blockIdx.x & 127) * 32;
    const int jj = jb + (t & 31), seg = t >> 5;
    const float* p = part + (long)b * NPB * 4096 + jj;
    float s = 0.f;
    for (int pb = seg; pb < NPB; pb += 8) s += p[(long)pb * 4096];
    red[seg][t & 31] = s;
    __syncthreads();
    if (t < 32) {
        float r = 0.f;
        #pragma unroll
        for (int q = 0; q < 8; ++q) r += red[q][t];
        Wf[b * 4096 + jb + t] = r;
    }
}

// ---------------------------------------------------------------------------
// vmat (R15, unchanged)
// ---------------------------------------------------------------------------
__global__ __launch_bounds__(256)
void vmat_kernel(const float* __restrict__ Wf, const float* __restrict__ ma,
                 const float* __restrict__ mu, const float* __restrict__ fcw,
                 unsigned short* __restrict__ Vb)
{
    __shared__ float Ws[4096];
    __shared__ float Qs[32][32];
    const int t = threadIdx.x, b = blockIdx.x;
    for (int i = t; i < 4096; i += 256) Ws[i] = Wf[b * 4096 + i];
    __syncthreads();
    for (int i = t; i < 1024; i += 256) {
        int o = i >> 5, ii = i & 31;
        float s = 0.f;
        for (int f = 0; f < 64; ++f) s += mu[f*32 + o] * ma[f*32 + ii];
        Qs[o][ii] = s;
    }
    __syncthreads();
    const float invN = 1.f / 262144.f;
    for (int i = t; i < 5120; i += 256) {
        int k = i >> 5, o = i & 31;
        float v;
        if (k < 128) {
            int g = k & 63, off = (k >= 64) ? 64 : 0;
            float s = 0.f;
            for (int q = 0; q < 32; ++q) s += Qs[o][q] * Ws[q*128 + off + g];
            v = s * invN;
        } else {
            v = fcw[(k - 128) * 32 + o];
        }
        Vb[b * 5120 + i] = bf16_rn(v);
    }
}

// ---------------------------------------------------------------------------
// Pass 2 (R15, unchanged)
// ---------------------------------------------------------------------------
template<bool READ_ABF>
__global__ __launch_bounds__(256)
void pass2_kernel(const float* __restrict__ a, const unsigned* __restrict__ abf,
                  const float* __restrict__ x, const unsigned short* __restrict__ Vb,
                  const float* __restrict__ fcb, const float* __restrict__ my,
                  float* __restrict__ out)
{
    __shared__ float4 xs[4][32];
    __shared__ float4 mys[64];
    __shared__ __align__(16) float st[4][16][32];
    const int t = threadIdx.x, wave = t >> 6, lane = t & 63;
    const int l15 = lane & 15, l4 = lane >> 4;
    const int blk = blockIdx.x, b = blk >> 9, lb = blk & 511;
    const long base = (long)b * NPTS + (long)lb * 512;

    if (t < 64) { const float* mq = my + t*3; mys[t] = make_float4(mq[0], mq[1], mq[2], 0.f); }

    bf16x8 bfr[5][2];
    {
        const unsigned short* vb = Vb + b * 5120;
        #pragma unroll
        for (int c = 0; c < 5; ++c)
            #pragma unroll
            for (int ct = 0; ct < 2; ++ct) {
                bf16x8 tmp;
                #pragma unroll
                for (int j = 0; j < 8; ++j) {
                    unsigned short uv = vb[(32*c + l4*8 + j) * 32 + l15 + 16*ct];
                    tmp[j] = __builtin_bit_cast(__bf16, uv);
                }
                bfr[c][ct] = tmp;
            }
    }
    const float bias0 = fcb[l15], bias1 = fcb[l15 + 16];
    __syncthreads();

    for (int ci = wave; ci < 16; ci += 4) {
        const long pc = base + ((long)ci << 5);

        if (lane < 32) {
            const float* xq = x + (pc + lane) * 3;
            xs[wave][lane] = make_float4(xq[0], xq[1], xq[2], 0.f);
        }
        bf16x8 afr[2];
        #pragma unroll
        for (int rt = 0; rt < 2; ++rt) {
            if (READ_ABF) {
                afr[rt] = __builtin_bit_cast(bf16x8,
                    *(const uint4*)(abf + (pc + l15 + 16*rt) * 16 + l4*4));
            } else {
                const float* ap = a + (pc + l15 + 16*rt) * 32 + l4*8;
                float4 a0 = *(const float4*)ap;
                float4 a1 = *(const float4*)(ap + 4);
                afr[rt][0] = (__bf16)a0.x; afr[rt][1] = (__bf16)a0.y;
                afr[rt][2] = (__bf16)a0.z; afr[rt][3] = (__bf16)a0.w;
                afr[rt][4] = (__bf16)a1.x; afr[rt][5] = (__bf16)a1.y;
                afr[rt][6] = (__bf16)a1.z; afr[rt][7] = (__bf16)a1.w;
            }
        }

        float4 xp0 = xs[wave][l15];
        float4 xp1 = xs[wave][l15 + 16];

        f32x4 acc[2][2];
        #pragma unroll
        for (int rt = 0; rt < 2; ++rt)
            #pragma unroll
            for (int ct = 0; ct < 2; ++ct) acc[rt][ct] = f32x4{0.f,0.f,0.f,0.f};

        #pragma unroll
        for (int gt = 0; gt < 2; ++gt) {
            bf16x8 ac[2], as2[2];
            #pragma unroll
            for (int j = 0; j < 8; ++j) {
                float4 m = mys[gt*32 + l4*8 + j];
                float d0 = xp0.x*m.x + xp0.y*m.y + xp0.z*m.z;
                float d1 = xp1.x*m.x + xp1.y*m.y + xp1.z*m.z;
                ac[0][j]  = (__bf16)__builtin_amdgcn_cosf(d0);
                as2[0][j] = (__bf16)__builtin_amdgcn_sinf(d0);
                ac[1][j]  = (__bf16)__builtin_amdgcn_cosf(d1);
                as2[1][j] = (__bf16)__builtin_amdgcn_sinf(d1);
            }
            #pragma unroll
            for (int rt = 0; rt < 2; ++rt)
                #pragma unroll
                for (int ct = 0; ct < 2; ++ct) {
                    acc[rt][ct] = __builtin_amdgcn_mfma_f32_16x16x32_bf16(ac[rt],  bfr[gt][ct],   acc[rt][ct], 0, 0, 0);
                    acc[rt][ct] = __builtin_amdgcn_mfma_f32_16x16x32_bf16(as2[rt], bfr[2+gt][ct], acc[rt][ct], 0, 0, 0);
                }
        }
        #pragma unroll
        for (int rt = 0; rt < 2; ++rt) {
            #pragma unroll
            for (int ct = 0; ct < 2; ++ct) {
                acc[rt][ct] = __builtin_amdgcn_mfma_f32_16x16x32_bf16(afr[rt], bfr[4][ct], acc[rt][ct], 0, 0, 0);
                float bias = ct ? bias1 : bias0;
                #pragma unroll
                for (int r = 0; r < 4; ++r)
                    st[wave][l4*4 + r][l15 + 16*ct] = gelu_fast(acc[rt][ct][r] + bias);
            }
            {
                int row = lane >> 3;
                int c4  = (lane & 7) * 4;
                float4 v0 = *(const float4*)&st[wave][row][c4];
                float4 v1 = *(const float4*)&st[wave][row + 8][c4];
                *(float4*)&out[(pc + 16*rt + row) * 32 + c4]     = v0;
                *(float4*)&out[(pc + 16*rt + row + 8) * 32 + c4] = v1;
            }
        }
    }
}

// ---------------------------------------------------------------------------
extern "C" void kernel_launch(void* const* d_in, const int* in_sizes, int n_in,
                              void* d_out, int out_size, void* d_ws, size_t ws_size,
                              hipStream_t stream)
{
    const float* a   = (const float*)d_in[0];
    const float* x   = (const float*)d_in[1];
    const float* ma  = (const float*)d_in[3];
    const float* mx  = (const float*)d_in[4];
    const float* my  = (const float*)d_in[5];
    const float* mu  = (const float*)d_in[6];
    const float* fcw = (const float*)d_in[7];
    const float* fcb = (const float*)d_in[8];
    float* out = (float*)d_out;

    const size_t WfB  = (size_t)NB * 4096 * 4;
    const size_t VbB  = (size_t)NB * 5120 * 2;
    const size_t abfB = (size_t)NB * NPTS * 16 * 4;   // 33.5 MB u32 relay

    int NPB = 256;
    bool use_abf = ws_size >= (size_t)NB * NPB * 4096 * 4 + WfB + VbB + abfB + 256;
    if (!use_abf) {
        while (NPB > 32 &&
               ws_size < (size_t)NB * NPB * 4096 * 4 + WfB + VbB + 256)
            NPB >>= 1;
    }

    float* part = (float*)d_ws;
    float* Wf = part + (size_t)NB * NPB * 4096;
    unsigned short* Vb = (unsigned short*)(Wf + NB * 4096);
    unsigned* abf = (unsigned*)(Vb + NB * 5120);

    if (use_abf)
        pass1_kernel<true><<<NB * NPB, 256, 0, stream>>>(a, x, mx, part, abf, NPB);
    else
        pass1_kernel<false><<<NB * NPB, 256, 0, stream>>>(a, x, mx, part, abf, NPB);

    reduceW_kernel<<<NB * 128, 256, 0, stream>>>(part, Wf, NPB);
    vmat_kernel<<<NB, 256, 0, stream>>>(Wf, ma, mu, fcw, Vb);

    if (use_abf)
        pass2_kernel<true><<<NB * 512, 256, 0, stream>>>(a, abf, x, Vb, fcb, my, out);
    else
        pass2_kernel<false><<<NB * 512, 256, 0, stream>>>(a, abf, x, Vb, fcb, my, out);
}